// Round 1
// baseline (302.999 us; speedup 1.0000x reference)
//
#include <hip/hip_runtime.h>

// DynamicFC: out[b,o,h,w] = sum_i w[b,o,i] * x[b,i,h,w] + bias[b,o]
// Batched GEMM per b: M=Cout=512, N=HW=784, K=Cin=512, fp32 in/out.
// Strategy: fp32 -> bf16 convert during LDS staging, mfma_f32_16x16x32_bf16,
// fp32 accumulate. 128x128 C-tile per block, 4 waves (2x2), each wave 64x64
// (4x4 fragments of 16x16). K-step = 32.

#define CIN  512
#define COUT 512
#define HW   784      // 28*28
#define BM   128
#define BN   128
#define BK   32
#define LDS_STRIDE 40 // 32 + 8 pad (keeps 16B alignment, balances banks)

typedef __bf16 bf16_t;
typedef __bf16 bf16x8 __attribute__((ext_vector_type(8)));
typedef __bf16 bf16x4 __attribute__((ext_vector_type(4)));
typedef float  f32x4  __attribute__((ext_vector_type(4)));

__device__ __forceinline__ bf16x8 pack8(f32x4 a, f32x4 b) {
    bf16x8 r;
    r[0] = (bf16_t)a[0]; r[1] = (bf16_t)a[1];
    r[2] = (bf16_t)a[2]; r[3] = (bf16_t)a[3];
    r[4] = (bf16_t)b[0]; r[5] = (bf16_t)b[1];
    r[6] = (bf16_t)b[2]; r[7] = (bf16_t)b[3];
    return r;
}

__global__ __launch_bounds__(256) void dynfc_kernel(
    const float* __restrict__ x,     // [64][512][784]
    const float* __restrict__ w,     // [64][512][512]
    const float* __restrict__ bias,  // [64][512]
    float* __restrict__ out)         // [64][512][784]
{
    __shared__ bf16_t Asm[BM * LDS_STRIDE];   // [m][k], k-contiguous
    __shared__ bf16_t Bsm[BN * LDS_STRIDE];   // [n][k], k-contiguous (B^T form)
    __shared__ float  bias_sm[BM];

    const int bid   = blockIdx.x;
    const int batch = bid / 28;          // 4 m-tiles * 7 n-tiles per batch
    const int trem  = bid % 28;
    const int tm    = trem / 7;
    const int tn    = trem % 7;
    const int m0    = tm * BM;
    const int n0    = tn * BN;

    const int tid  = threadIdx.x;
    const int lane = tid & 63;
    const int wid  = tid >> 6;
    const int wm   = (wid & 1) * 64;     // wave's m offset inside tile
    const int wn   = (wid >> 1) * 64;    // wave's n offset inside tile
    const int l15  = lane & 15;
    const int quad = lane >> 4;

    const float* xb = x + (size_t)batch * CIN * HW;
    const float* wb = w + (size_t)batch * COUT * CIN;

    if (tid < 32) {
        f32x4 bv = *(const f32x4*)(bias + batch * COUT + m0 + tid * 4);
        *(f32x4*)&bias_sm[tid * 4] = bv;
    }

    // A staging: thread -> (row ar of 128, k-half ah of {0,16}); 16 fp32 each
    const int ar = tid >> 1;
    const int ah = (tid & 1) * 16;
    // B staging: thread -> 4x4 micro-tile; kg = k-group (0..7), ng = n-group (0..31)
    const int kg = tid & 7;
    const int ng = tid >> 3;
    int nb = n0 + ng * 4;
    if (nb > HW - 4) nb = HW - 4;        // clamp: loads stay in-bounds; bad cols masked at store

    f32x4 acc[4][4] = {};

    for (int k0 = 0; k0 < CIN; k0 += BK) {
        __syncthreads();
        // ---- stage A (weight): 128 rows x 32 k, direct (k-contiguous) ----
        {
            const float* src = wb + (size_t)(m0 + ar) * CIN + k0 + ah;
            f32x4 v0 = *(const f32x4*)(src);
            f32x4 v1 = *(const f32x4*)(src + 4);
            f32x4 v2 = *(const f32x4*)(src + 8);
            f32x4 v3 = *(const f32x4*)(src + 12);
            *(bf16x8*)&Asm[ar * LDS_STRIDE + ah]     = pack8(v0, v1);
            *(bf16x8*)&Asm[ar * LDS_STRIDE + ah + 8] = pack8(v2, v3);
        }
        // ---- stage B (input): 32 k x 128 n, 4x4 register transpose ----
        {
            const float* src = xb + (size_t)(k0 + kg * 4) * HW + nb;
            f32x4 r0 = *(const f32x4*)(src);
            f32x4 r1 = *(const f32x4*)(src + HW);
            f32x4 r2 = *(const f32x4*)(src + 2 * HW);
            f32x4 r3 = *(const f32x4*)(src + 3 * HW);
            #pragma unroll
            for (int nn = 0; nn < 4; nn++) {
                bf16x4 col;
                col[0] = (bf16_t)r0[nn];
                col[1] = (bf16_t)r1[nn];
                col[2] = (bf16_t)r2[nn];
                col[3] = (bf16_t)r3[nn];
                *(bf16x4*)&Bsm[(ng * 4 + nn) * LDS_STRIDE + kg * 4] = col;
            }
        }
        __syncthreads();
        // ---- fragments + MFMA ----
        bf16x8 af[4], bf[4];
        #pragma unroll
        for (int i = 0; i < 4; i++)
            af[i] = *(const bf16x8*)&Asm[(wm + i * 16 + l15) * LDS_STRIDE + quad * 8];
        #pragma unroll
        for (int j = 0; j < 4; j++)
            bf[j] = *(const bf16x8*)&Bsm[(wn + j * 16 + l15) * LDS_STRIDE + quad * 8];
        #pragma unroll
        for (int i = 0; i < 4; i++)
            #pragma unroll
            for (int j = 0; j < 4; j++)
                acc[i][j] = __builtin_amdgcn_mfma_f32_16x16x32_bf16(af[i], bf[j], acc[i][j], 0, 0, 0);
    }

    // ---- epilogue: add bias, guarded store (C/D: col = lane&15, row = quad*4+r) ----
    float* ob = out + (size_t)batch * COUT * HW;
    #pragma unroll
    for (int j = 0; j < 4; j++) {
        int n = n0 + wn + j * 16 + l15;
        if (n < HW) {
            #pragma unroll
            for (int i = 0; i < 4; i++) {
                #pragma unroll
                for (int r = 0; r < 4; r++) {
                    int m = wm + i * 16 + quad * 4 + r;
                    ob[(size_t)(m0 + m) * HW + n] = acc[i][j][r] + bias_sm[m];
                }
            }
        }
    }
}

extern "C" void kernel_launch(void* const* d_in, const int* in_sizes, int n_in,
                              void* d_out, int out_size, void* d_ws, size_t ws_size,
                              hipStream_t stream) {
    (void)in_sizes; (void)n_in; (void)d_ws; (void)ws_size; (void)out_size;
    const float* x    = (const float*)d_in[0];
    const float* w    = (const float*)d_in[1];
    const float* bias = (const float*)d_in[2];
    float* out        = (float*)d_out;

    dim3 grid(64 * 4 * 7);   // 64 batches * 4 m-tiles * 7 n-tiles
    dim3 block(256);
    dynfc_kernel<<<grid, block, 0, stream>>>(x, w, bias, out);
}

// Round 2
// 287.665 us; speedup vs baseline: 1.0533x; 1.0533x over previous
//
#include <hip/hip_runtime.h>

// DynamicFC: out[b,o,h,w] = sum_i w[b,o,i] * x[b,i,h,w] + bias[b,o]
// Batched GEMM per b: M=Cout=512, N=HW=784, K=Cin=512, fp32 in/out.
// fp32 -> bf16 convert during LDS staging, mfma_f32_16x16x32_bf16, fp32 acc.
// 128x128 C-tile per block, 4 waves (2x2), each wave 64x64 (4x4 frags).
// R2: XCD-aware swizzle (batch b -> XCD b%8 so its 2.6 MB working set lives
// in one 4 MB L2) + nontemporal C stores (don't evict X/W from L2).

#define CIN  512
#define COUT 512
#define HW   784      // 28*28
#define BM   128
#define BN   128
#define BK   32
#define LDS_STRIDE 40 // 32 + 8 pad (keeps 16B alignment, balances banks)

typedef __bf16 bf16_t;
typedef __bf16 bf16x8 __attribute__((ext_vector_type(8)));
typedef __bf16 bf16x4 __attribute__((ext_vector_type(4)));
typedef float  f32x4  __attribute__((ext_vector_type(4)));

__device__ __forceinline__ bf16x8 pack8(f32x4 a, f32x4 b) {
    bf16x8 r;
    r[0] = (bf16_t)a[0]; r[1] = (bf16_t)a[1];
    r[2] = (bf16_t)a[2]; r[3] = (bf16_t)a[3];
    r[4] = (bf16_t)b[0]; r[5] = (bf16_t)b[1];
    r[6] = (bf16_t)b[2]; r[7] = (bf16_t)b[3];
    return r;
}

__global__ __launch_bounds__(256) void dynfc_kernel(
    const float* __restrict__ x,     // [64][512][784]
    const float* __restrict__ w,     // [64][512][512]
    const float* __restrict__ bias,  // [64][512]
    float* __restrict__ out)         // [64][512][784]
{
    __shared__ bf16_t Asm[BM * LDS_STRIDE];   // [m][k], k-contiguous
    __shared__ bf16_t Bsm[BN * LDS_STRIDE];   // [n][k], k-contiguous (B^T form)
    __shared__ float  bias_sm[BM];

    // XCD swizzle: HW maps blockIdx round-robin across 8 XCDs -> give each
    // XCD whole batches so W (1MB) + X (1.6MB) re-reads hit that XCD's L2.
    const int bid   = blockIdx.x;        // 0..1791
    const int xcd   = bid & 7;
    const int j     = bid >> 3;          // 0..223
    const int batch = xcd + 8 * (j / 28);
    const int trem  = j % 28;
    const int tm    = trem / 7;
    const int tn    = trem % 7;
    const int m0    = tm * BM;
    const int n0    = tn * BN;

    const int tid  = threadIdx.x;
    const int lane = tid & 63;
    const int wid  = tid >> 6;
    const int wm   = (wid & 1) * 64;     // wave's m offset inside tile
    const int wn   = (wid >> 1) * 64;    // wave's n offset inside tile
    const int l15  = lane & 15;
    const int quad = lane >> 4;

    const float* xb = x + (size_t)batch * CIN * HW;
    const float* wb = w + (size_t)batch * COUT * CIN;

    if (tid < 32) {
        f32x4 bv = *(const f32x4*)(bias + batch * COUT + m0 + tid * 4);
        *(f32x4*)&bias_sm[tid * 4] = bv;
    }

    // A staging: thread -> (row ar of 128, k-half ah of {0,16}); 16 fp32 each
    const int ar = tid >> 1;
    const int ah = (tid & 1) * 16;
    // B staging: thread -> 4x4 micro-tile; kg = k-group (0..7), ng = n-group (0..31)
    const int kg = tid & 7;
    const int ng = tid >> 3;
    int nb = n0 + ng * 4;
    if (nb > HW - 4) nb = HW - 4;        // clamp: loads stay in-bounds; bad cols masked at store

    f32x4 acc[4][4] = {};

    for (int k0 = 0; k0 < CIN; k0 += BK) {
        __syncthreads();
        // ---- stage A (weight): 128 rows x 32 k, direct (k-contiguous) ----
        {
            const float* src = wb + (size_t)(m0 + ar) * CIN + k0 + ah;
            f32x4 v0 = *(const f32x4*)(src);
            f32x4 v1 = *(const f32x4*)(src + 4);
            f32x4 v2 = *(const f32x4*)(src + 8);
            f32x4 v3 = *(const f32x4*)(src + 12);
            *(bf16x8*)&Asm[ar * LDS_STRIDE + ah]     = pack8(v0, v1);
            *(bf16x8*)&Asm[ar * LDS_STRIDE + ah + 8] = pack8(v2, v3);
        }
        // ---- stage B (input): 32 k x 128 n, 4x4 register transpose ----
        {
            const float* src = xb + (size_t)(k0 + kg * 4) * HW + nb;
            f32x4 r0 = *(const f32x4*)(src);
            f32x4 r1 = *(const f32x4*)(src + HW);
            f32x4 r2 = *(const f32x4*)(src + 2 * HW);
            f32x4 r3 = *(const f32x4*)(src + 3 * HW);
            #pragma unroll
            for (int nn = 0; nn < 4; nn++) {
                bf16x4 col;
                col[0] = (bf16_t)r0[nn];
                col[1] = (bf16_t)r1[nn];
                col[2] = (bf16_t)r2[nn];
                col[3] = (bf16_t)r3[nn];
                *(bf16x4*)&Bsm[(ng * 4 + nn) * LDS_STRIDE + kg * 4] = col;
            }
        }
        __syncthreads();
        // ---- fragments + MFMA ----
        bf16x8 af[4], bf[4];
        #pragma unroll
        for (int i = 0; i < 4; i++)
            af[i] = *(const bf16x8*)&Asm[(wm + i * 16 + l15) * LDS_STRIDE + quad * 8];
        #pragma unroll
        for (int j2 = 0; j2 < 4; j2++)
            bf[j2] = *(const bf16x8*)&Bsm[(wn + j2 * 16 + l15) * LDS_STRIDE + quad * 8];
        #pragma unroll
        for (int i = 0; i < 4; i++)
            #pragma unroll
            for (int j2 = 0; j2 < 4; j2++)
                acc[i][j2] = __builtin_amdgcn_mfma_f32_16x16x32_bf16(af[i], bf[j2], acc[i][j2], 0, 0, 0);
    }

    // ---- epilogue: add bias, guarded nontemporal store ----
    // C/D layout: col = lane&15, row = quad*4 + r
    float* ob = out + (size_t)batch * COUT * HW;
    #pragma unroll
    for (int j2 = 0; j2 < 4; j2++) {
        int n = n0 + wn + j2 * 16 + l15;
        if (n < HW) {
            #pragma unroll
            for (int i = 0; i < 4; i++) {
                #pragma unroll
                for (int r = 0; r < 4; r++) {
                    int m = wm + i * 16 + quad * 4 + r;
                    __builtin_nontemporal_store(acc[i][j2][r] + bias_sm[m],
                                                &ob[(size_t)(m0 + m) * HW + n]);
                }
            }
        }
    }
}

extern "C" void kernel_launch(void* const* d_in, const int* in_sizes, int n_in,
                              void* d_out, int out_size, void* d_ws, size_t ws_size,
                              hipStream_t stream) {
    (void)in_sizes; (void)n_in; (void)d_ws; (void)ws_size; (void)out_size;
    const float* x    = (const float*)d_in[0];
    const float* w    = (const float*)d_in[1];
    const float* bias = (const float*)d_in[2];
    float* out        = (float*)d_out;

    dim3 grid(64 * 4 * 7);   // 64 batches * 4 m-tiles * 7 n-tiles
    dim3 block(256);
    dynfc_kernel<<<grid, block, 0, stream>>>(x, w, bias, out);
}